// Round 15
// baseline (293.156 us; speedup 1.0000x reference)
//
#include <hip/hip_runtime.h>
#include <hip/hip_fp16.h>

#define NN 100000
#define NE 1600000
#define N64 (NN * 64)
#define NB 1563                       // buckets = dst>>6 (ceil(100000/64))
#define CAP2 1280                     // bucket capacity (mean ~1024, +8 sigma)
#define P1STRIDE (CAP2 * 2)           // dwords per bucket slot (u32 payload + dump room)
#define MLP1_BLKS 391                 // mlp1 role: block covers 256 nodes x 4 quarters
#define BKT_BLKS 196                  // 196 * 1024 * 8 >= NE
#define FUSED_BLKS 588                // 2:1 interleave grid (idle mlp1 slot = frag prep)
#define MAXT 148                      // max tiles/bucket: 64 + (1280-64)/16 = 140, +pad

typedef __attribute__((ext_vector_type(8))) _Float16 f16x8;
typedef __attribute__((ext_vector_type(4))) float fx4;

// ---- workspace layout (dword offsets) ----
#define WB1F_OFF 9216                 // f16 Wb frags layer1: 2048 dwords
#define WB2F_OFF 11264                // layer2: 2048 dwords
#define W2C_OFF 13312                 // combined f16 W2a frags (Wd||Ws): 4096 dwords
#define GCUR_OFF 17408                // bucket cursors [NB]
#define A_OFF   32768                 // packed f16: 32 dwords/node (layer-1 A)
#define B_OFF   (A_OFF + N64 / 2)     // layer-1 B
#define G1_OFF  (B_OFF + N64 / 2)     // layer-2 A features (written by edge1 epilogue)
#define G2_OFF  (G1_OFF + N64 / 2)    // layer-2 B features
#define P1_OFF  (G2_OFF + N64 / 2)    // u32[NB*P1STRIDE] bucket staging
// p1 slot (P1STRIDE dwords per bucket):
//   scatter phase: [0..size)  u32 payload = src | dloc<<17  (src<2^17, dloc 6b)
//   after layer-1 sort dump:  [0..CAP2) sorted src ids; [CAP2] = T;
//                             [CAP2+1..CAP2+1+MAXT) tile descriptors

union FragH { unsigned u[4]; f16x8 f; };

static __device__ __forceinline__ unsigned pack_h2(float f0, float f1) {
    __half h0 = __float2half_rn(f0), h1 = __float2half_rn(f1);
    unsigned short u0 = *(unsigned short*)&h0, u1 = *(unsigned short*)&h1;
    return (unsigned)u0 | ((unsigned)u1 << 16);
}

// Fused mlp1 + bucket multisplit (R36): R35's 2:1 role interleave, plus:
//  - prep_all kernel ELIMINATED. gcur zeroing -> hipMemsetAsync;
//    W1D/W1S precombine -> inline in the mlp1 role (wave-uniform scalar
//    loads of W1a, diff computed once, both output passes share one loop);
//    Wb/W2C fragment prep -> the grid's one idle block (mid==391), whose
//    output is consumed only by edge1/edge2 (after kernel boundary).
__global__ __launch_bounds__(1024) void fused_mlp1_bucket(
    const float* __restrict__ x, const float* __restrict__ W1a,
    const float* __restrict__ ba,
    const float* __restrict__ W1b, const float* __restrict__ W2a,
    const float* __restrict__ W2b, float* __restrict__ ws,
    unsigned* __restrict__ A16, unsigned* __restrict__ Bu,
    const int* __restrict__ src, const int* __restrict__ dst,
    int* __restrict__ gcur, unsigned* __restrict__ p1u)
{
    __shared__ int cnt[NB];
    __shared__ int cur[NB];
    const int t = threadIdx.x;
    const int g = blockIdx.x / 3, r = blockIdx.x % 3;

    if (r != 2) {
        const int mid = 2 * g + r;               // mlp1 role
        if (mid == MLP1_BLKS) {                  // idle slot -> weight-frag prep
#pragma unroll
            for (int it = 0; it < 2; ++it) {
                const int t2 = it * 1024 + t;    // 0..2047
                if (t2 < 1024) {
                    const int layer = t2 >> 9;
                    const int r2 = t2 & 511;
                    const int ks = (r2 >> 8) & 1, nt = (r2 >> 6) & 3, lane = r2 & 63;
                    const float* Wb = layer ? W2b : W1b;
                    int* out = (int*)(ws + (layer ? WB2F_OFF : WB1F_OFF));
                    const int quad = lane >> 4, c = lane & 15, n = nt * 16 + c;
                    unsigned dw[4];
#pragma unroll
                    for (int d = 0; d < 4; ++d) {
                        int k0 = quad * 8 + d * 2 + 32 * ks;
                        dw[d] = pack_h2(Wb[k0 * 64 + n], Wb[(k0 + 1) * 64 + n]);
                    }
                    ((int4*)out)[r2] = make_int4((int)dw[0], (int)dw[1],
                                                 (int)dw[2], (int)dw[3]);
                } else {
                    const int r2 = t2 - 1024;    // ks*512 + nt8*64 + lane
                    const int ks = (r2 >> 9) & 1, nt8 = (r2 >> 6) & 7, lane = r2 & 63;
                    const int quad = lane >> 4, c = lane & 15;
                    const int ncol = nt8 * 16 + c;
                    int* out = (int*)(ws + W2C_OFF);
                    unsigned dw[4];
#pragma unroll
                    for (int d = 0; d < 4; ++d) {
                        unsigned v[2];
#pragma unroll
                        for (int e = 0; e < 2; ++e) {
                            int k = quad * 8 + d * 2 + e + 32 * ks;
                            float w = (ncol < 64)
                                ? (W2a[k * 64 + ncol] - W2a[(64 + k) * 64 + ncol])
                                : W2a[(64 + k) * 64 + (ncol - 64)];
                            __half h = __float2half_rn(w);
                            v[e] = *(unsigned short*)&h;
                        }
                        dw[d] = (v[1] << 16) | v[0];
                    }
                    ((int4*)out)[r2] = make_int4((int)dw[0], (int)dw[1],
                                                 (int)dw[2], (int)dw[3]);
                }
            }
            return;
        }
        const int q = t >> 8;
        const int i = mid * 256 + (t & 255);
        if (i >= NN) return;
        float xv[7];
#pragma unroll
        for (int k = 0; k < 7; ++k) xv[k] = x[i * 7 + k];
        uint4* pa = (uint4*)(A16 + (size_t)i * 32 + q * 8);
        uint4* pb = (uint4*)(Bu + (size_t)i * 32 + q * 8);
        float accA[16], accB[16];
#pragma unroll
        for (int c = 0; c < 16; ++c) { accA[c] = ba[q * 16 + c]; accB[c] = 0.f; }
#pragma unroll
        for (int k = 0; k < 7; ++k)
#pragma unroll
            for (int c = 0; c < 16; ++c) {
                const float wb_ = W1a[448 + k * 64 + q * 16 + c]; // bottom
                const float wt_ = W1a[k * 64 + q * 16 + c];       // top
                accA[c] = fmaf(xv[k], wt_ - wb_, accA[c]);
                accB[c] = fmaf(xv[k], wb_, accB[c]);
            }
        pa[0] = make_uint4(pack_h2(accA[0], accA[1]),  pack_h2(accA[2], accA[3]),
                           pack_h2(accA[4], accA[5]),  pack_h2(accA[6], accA[7]));
        pa[1] = make_uint4(pack_h2(accA[8], accA[9]),  pack_h2(accA[10], accA[11]),
                           pack_h2(accA[12], accA[13]), pack_h2(accA[14], accA[15]));
        pb[0] = make_uint4(pack_h2(accB[0], accB[1]),  pack_h2(accB[2], accB[3]),
                           pack_h2(accB[4], accB[5]),  pack_h2(accB[6], accB[7]));
        pb[1] = make_uint4(pack_h2(accB[8], accB[9]),  pack_h2(accB[10], accB[11]),
                           pack_h2(accB[12], accB[13]), pack_h2(accB[14], accB[15]));
        return;
    }

    // ---- bucket role (bb = g) ----
    const int e0 = (g * 1024 + t) * 8;
    const bool ok = (e0 < NE);                   // NE % 8 == 0
    for (int i = t; i < NB; i += 1024) cnt[i] = 0;
    int ss[8], dd[8], bk[8];
    if (ok) {
        int4 d0 = ((const int4*)(dst + e0))[0];
        int4 d1 = ((const int4*)(dst + e0))[1];
        int4 s0 = ((const int4*)(src + e0))[0];
        int4 s1 = ((const int4*)(src + e0))[1];
        dd[0]=d0.x; dd[1]=d0.y; dd[2]=d0.z; dd[3]=d0.w;
        dd[4]=d1.x; dd[5]=d1.y; dd[6]=d1.z; dd[7]=d1.w;
        ss[0]=s0.x; ss[1]=s0.y; ss[2]=s0.z; ss[3]=s0.w;
        ss[4]=s1.x; ss[5]=s1.y; ss[6]=s1.z; ss[7]=s1.w;
    }
    __syncthreads();
    if (ok) {
#pragma unroll
        for (int j = 0; j < 8; ++j) { bk[j] = dd[j] >> 6; atomicAdd(&cnt[bk[j]], 1); }
    }
    __syncthreads();
    for (int i = t; i < NB; i += 1024)
        cur[i] = atomicAdd(&gcur[i], cnt[i]);    // reserve block ranges
    __syncthreads();
    if (ok) {
#pragma unroll
        for (int j = 0; j < 8; ++j) {
            int pos = atomicAdd(&cur[bk[j]], 1);
            p1u[(size_t)bk[j] * P1STRIDE + pos] =
                (unsigned)ss[j] | ((unsigned)(dd[j] & 63) << 17);
        }
    }
}

// ---- shared phase-4 tile loop (R29-exact structure; R36 adds s_setprio(1)
// around the MFMA cluster -- the loop is barrier-free independent-wave, the
// regime where setprio measured +4-7%; lockstep GEMM was the null case).
#define EDGE_PHASE4                                                           \
    const int nb64 = b * 64;                                                  \
    for (int t0 = wv * 2; t0 < T; t0 += 8) {                                  \
        const int2 tp = ((const int2*)tiles)[t0 >> 1];                        \
        const int n0 = tp.x & 63, ba0 = (tp.x >> 6) & 2047, c0 = tp.x >> 17;  \
        const int n1 = tp.y & 63, ba1 = (tp.y >> 6) & 2047, c1 = tp.y >> 17;  \
        const int s0 = ssrc[ba0 + min(c15, c0 - 1)];                          \
        const int s1 = ssrc[ba1 + min(c15, c1 - 1)];                          \
        const unsigned* pa0 = A16 + (size_t)(nb64 + n0) * 32 + quad * 4;      \
        const unsigned* pa1 = A16 + (size_t)(nb64 + n1) * 32 + quad * 4;      \
        const unsigned* pb0 = Bu + (size_t)s0 * 32 + quad * 4;                \
        const unsigned* pb1 = Bu + (size_t)s1 * 32 + quad * 4;                \
        uint4 ga[2][2], gb[2][2];                                             \
        _Pragma("unroll")                                                     \
        for (int ks = 0; ks < 2; ++ks) {                                      \
            ga[0][ks] = ((const uint4*)(pa0 + ks * 16))[0];                   \
            gb[0][ks] = ((const uint4*)(pb0 + ks * 16))[0];                   \
            ga[1][ks] = ((const uint4*)(pa1 + ks * 16))[0];                   \
            gb[1][ks] = ((const uint4*)(pb1 + ks * 16))[0];                   \
        }                                                                     \
        FragH tf[2][2];                                                       \
        _Pragma("unroll")                                                     \
        for (int mt = 0; mt < 2; ++mt)                                        \
            _Pragma("unroll")                                                 \
            for (int ks = 0; ks < 2; ++ks) {                                  \
                FragH ua, ub;                                                 \
                ua.u[0] = ga[mt][ks].x; ua.u[1] = ga[mt][ks].y;               \
                ua.u[2] = ga[mt][ks].z; ua.u[3] = ga[mt][ks].w;               \
                ub.u[0] = gb[mt][ks].x; ub.u[1] = gb[mt][ks].y;               \
                ub.u[2] = gb[mt][ks].z; ub.u[3] = gb[mt][ks].w;               \
                f16x8 s = ua.f + ub.f;                                        \
                tf[mt][ks].f = __builtin_elementwise_max(                     \
                    s, (f16x8)(_Float16)0.0f);                                \
            }                                                                 \
        fx4 acc[2][4];                                                        \
        _Pragma("unroll")                                                     \
        for (int mt = 0; mt < 2; ++mt)                                        \
            _Pragma("unroll")                                                 \
            for (int nt = 0; nt < 4; ++nt)                                    \
                acc[mt][nt] = (fx4){0.f, 0.f, 0.f, 0.f};                      \
        __builtin_amdgcn_s_setprio(1);                                        \
        _Pragma("unroll")                                                     \
        for (int ks = 0; ks < 2; ++ks)                                        \
            _Pragma("unroll")                                                 \
            for (int mt = 0; mt < 2; ++mt)                                    \
                _Pragma("unroll")                                             \
                for (int nt = 0; nt < 4; ++nt)                                \
                    acc[mt][nt] = __builtin_amdgcn_mfma_f32_16x16x32_f16(     \
                        tf[mt][ks].f, wf[ks][nt].f, acc[mt][nt], 0, 0, 0);    \
        __builtin_amdgcn_s_setprio(0);                                        \
        const bool qb0 = (quad & 1) != 0, qb1 = (quad & 2) != 0;              \
        _Pragma("unroll")                                                     \
        for (int mt = 0; mt < 2; ++mt) {                                      \
            float rr[4];                                                      \
            _Pragma("unroll")                                                 \
            for (int nt = 0; nt < 4; ++nt)                                    \
                rr[nt] = fmaxf(fmaxf(acc[mt][nt][0], acc[mt][nt][1]),         \
                               fmaxf(acc[mt][nt][2], acc[mt][nt][3]));        \
            float u;                                                          \
            u = __shfl_xor(qb0 ? rr[0] : rr[1], 16);                          \
            if (qb0) rr[0] = u; else rr[1] = u;                               \
            u = __shfl_xor(qb0 ? rr[2] : rr[3], 16);                          \
            if (qb0) rr[2] = u; else rr[3] = u;                               \
            u = __shfl_xor(qb1 ? rr[0] : rr[2], 32);                          \
            if (qb1) rr[0] = u; else rr[2] = u;                               \
            u = __shfl_xor(qb1 ? rr[1] : rr[3], 32);                          \
            if (qb1) rr[1] = u; else rr[3] = u;                               \
            const float v = fmaxf(fmaxf(rr[0], rr[1]), fmaxf(rr[2], rr[3]));  \
            const float h = fmaxf(v + bcol, 0.f);                             \
            const int n = mt ? n1 : n0;                                       \
            atomicMax(&agg[n * 66 + lane], __float_as_uint(h));               \
        }                                                                     \
    }

// Edge layer 1 (sort + save + fused node-MLP2): node-major tiles after
// in-LDS counting sort; sorted ssrc/tiles dumped to the p1 slot for layer 2.
// Epilogue pushes the relu'd 64x64 agg tile through the [64->128] node-MLP2
// GEMM -> A2/B2 (must NOT touch A16/Bu: other blocks still gather them).
// LAUNCH BOUNDS LAW (R18/R22/R23/R24/R32): arch-VGPR cap ~= 512/(2N):
//   bound 4 -> 64 (FITS); bound 5 -> 48 (SPILLS even with wf in LDS, R32);
//   bound 6/7 -> 40/36 (heavy spill). THIS BODY STAYS AT BOUND 4.
__global__ __launch_bounds__(256, 4) void edge_layer_bucket(
    const unsigned* __restrict__ A16, const unsigned* __restrict__ Bu,
    unsigned* __restrict__ p1u, const int* __restrict__ gcnt,
    const int* __restrict__ wbf, const float* __restrict__ bb,
    const int* __restrict__ wcf, const float* __restrict__ ba2,
    unsigned* __restrict__ A2, unsigned* __restrict__ B2)
{
    __shared__ unsigned agg[64 * 66];            // 16,896 B
    __shared__ int cnt[64];
    __shared__ int cur[64];
    __shared__ int ssrc[CAP2];                   // 5,120 B
    __shared__ __align__(8) int tiles[MAXT];
    __shared__ int tcnt_s;

    const int tid = threadIdx.x;
    const int wv = tid >> 6, lane = tid & 63;
    const int quad = lane >> 4, c15 = lane & 15;
    const int b = blockIdx.x;
    const int size = min(gcnt[b], CAP2);         // clamp: never OOB ssrc/tiles
    const unsigned* bp = p1u + (size_t)b * P1STRIDE;

    for (int i = tid; i < 64 * 66; i += 256) agg[i] = 0u;
    if (tid < 64) cnt[tid] = 0;

    FragH wf[2][4];                              // persistent weight frags
#pragma unroll
    for (int ks = 0; ks < 2; ++ks)
#pragma unroll
        for (int nt = 0; nt < 4; ++nt) {
            int4 v = ((const int4*)wbf)[(ks * 4 + nt) * 64 + lane];
            wf[ks][nt].u[0] = (unsigned)v.x; wf[ks][nt].u[1] = (unsigned)v.y;
            wf[ks][nt].u[2] = (unsigned)v.z; wf[ks][nt].u[3] = (unsigned)v.w;
        }
    const float bcol = bb[lane];                 // channel == lane
    __syncthreads();

    // ---- phase 1: histogram (payload = src | dloc<<17) ----
    for (int i = tid; i < size; i += 256)
        atomicAdd(&cnt[bp[i] >> 17], 1);
    __syncthreads();

    // ---- phase 2: scan + tile list (wave 0 only) ----
    if (tid < 64) {
        const int c = cnt[tid];
        int x = c;
#pragma unroll
        for (int d = 1; d < 64; d <<= 1) {
            int y = __shfl_up(x, d, 64);
            if (lane >= d) x += y;
        }
        const int rs = x - c;                    // exclusive prefix (row start)
        cur[tid] = rs;
        const int ntl = (c + 15) >> 4;
        int tx = ntl;
#pragma unroll
        for (int d = 1; d < 64; d <<= 1) {
            int y = __shfl_up(tx, d, 64);
            if (lane >= d) tx += y;
        }
        const int tb = tx - ntl;
        for (int k = 0; k < ntl; ++k)            // node | base<<6 | cnt<<17
            tiles[tb + k] = tid | ((rs + 16 * k) << 6) | (min(16, c - 16 * k) << 17);
        if (tid == 63) tcnt_s = tx;
    }
    __syncthreads();
    const int T = tcnt_s;
    if (tid == 0 && T > 0) tiles[T] = tiles[T - 1];   // pad for int2 pair read

    // ---- phase 3: scatter src ids node-major ----
    __syncthreads();
    for (int i = tid; i < size; i += 256) {
        const unsigned w = bp[i];
        int p = atomicAdd(&cur[w >> 17], 1);
        ssrc[p] = (int)(w & 0x1FFFF);
    }
    __syncthreads();

    // ---- dump sorted order into this bucket's (now dead) p1 slot.
    // All bp reads completed before the barrier above; slot is block-private.
    {
        unsigned* dump = p1u + (size_t)b * P1STRIDE;
        for (int i = tid; i < size; i += 256) dump[i] = (unsigned)ssrc[i];
        if (tid == 0) dump[CAP2] = (unsigned)T;
        if (tid < MAXT) dump[CAP2 + 1 + tid] = (unsigned)tiles[tid];
    }

    EDGE_PHASE4
    __syncthreads();

    // ---- fused node-MLP2 epilogue: X = relu'd agg [64x64] -> A2/B2 [->128].
    // A-frag layout per node_mlp2's proven pattern: row = c15 (within this
    // wave's 16-node M-tile), k = ks*32 + quad*8 + (0..7).
    {
        const int arow = wv * 16 + c15;
        FragH xa[2];
#pragma unroll
        for (int ks = 0; ks < 2; ++ks) {
            const unsigned* ag = &agg[arow * 66 + ks * 32 + quad * 8];
#pragma unroll
            for (int d = 0; d < 4; ++d)
                xa[ks].u[d] = pack_h2(__uint_as_float(ag[2 * d]),
                                      __uint_as_float(ag[2 * d + 1]));
        }
        __half* Ah = (__half*)A2;
        __half* Bh = (__half*)B2;
#pragma unroll
        for (int nt = 0; nt < 8; ++nt) {
            FragH w0, w1;
            int4 v0 = ((const int4*)wcf)[nt * 64 + lane];
            int4 v1 = ((const int4*)wcf)[(8 + nt) * 64 + lane];
            w0.u[0] = (unsigned)v0.x; w0.u[1] = (unsigned)v0.y;
            w0.u[2] = (unsigned)v0.z; w0.u[3] = (unsigned)v0.w;
            w1.u[0] = (unsigned)v1.x; w1.u[1] = (unsigned)v1.y;
            w1.u[2] = (unsigned)v1.z; w1.u[3] = (unsigned)v1.w;
            fx4 acc2 = (fx4){0.f, 0.f, 0.f, 0.f};
            acc2 = __builtin_amdgcn_mfma_f32_16x16x32_f16(xa[0].f, w0.f, acc2, 0, 0, 0);
            acc2 = __builtin_amdgcn_mfma_f32_16x16x32_f16(xa[1].f, w1.f, acc2, 0, 0, 0);
            const float bbv = (nt < 4) ? ba2[nt * 16 + c15] : 0.f;
            __half* outh = (nt < 4) ? Ah : Bh;
            const int ch = (nt & 3) * 16 + c15;
#pragma unroll
            for (int r = 0; r < 4; ++r) {
                const int node = b * 64 + wv * 16 + quad * 4 + r;
                if (node < NN)
                    outh[(size_t)node * 64 + ch] = __float2half_rn(acc2[r] + bbv);
            }
        }
    }
}

// Edge layer 2 (load pre-sorted) + fused final linear: skips phases 1-3 via
// the p1 dump; writeout computes out[node] = h2 . Wl + bl directly from the
// relu'd agg rows in LDS (4 threads/node, 16-ch partials, 2x shfl_xor).
__global__ __launch_bounds__(256, 4) void edge_layer_bucket2(
    const unsigned* __restrict__ A16, const unsigned* __restrict__ Bu,
    const unsigned* __restrict__ p1s, const int* __restrict__ gcnt,
    const int* __restrict__ wbf, const float* __restrict__ bb,
    const float* __restrict__ Wl, const float* __restrict__ bl,
    float* __restrict__ outp)
{
    __shared__ unsigned agg[64 * 66];            // 16,896 B
    __shared__ int ssrc[CAP2];                   // 5,120 B
    __shared__ __align__(8) int tiles[MAXT];
    __shared__ int tcnt_s;

    const int tid = threadIdx.x;
    const int wv = tid >> 6, lane = tid & 63;
    const int quad = lane >> 4, c15 = lane & 15;
    const int b = blockIdx.x;
    const int size = min(gcnt[b], CAP2);
    const unsigned* slot = p1s + (size_t)b * P1STRIDE;

    for (int i = tid; i < 64 * 66; i += 256) agg[i] = 0u;
    if (tid == 0) tcnt_s = (int)slot[CAP2];
    if (tid < MAXT) tiles[tid] = (int)slot[CAP2 + 1 + tid];
    for (int i = tid; i < size; i += 256) ssrc[i] = (int)slot[i];

    FragH wf[2][4];
#pragma unroll
    for (int ks = 0; ks < 2; ++ks)
#pragma unroll
        for (int nt = 0; nt < 4; ++nt) {
            int4 v = ((const int4*)wbf)[(ks * 4 + nt) * 64 + lane];
            wf[ks][nt].u[0] = (unsigned)v.x; wf[ks][nt].u[1] = (unsigned)v.y;
            wf[ks][nt].u[2] = (unsigned)v.z; wf[ks][nt].u[3] = (unsigned)v.w;
        }
    const float bcol = bb[lane];
    __syncthreads();
    const int T = tcnt_s;

    EDGE_PHASE4
    __syncthreads();

    // fused final linear: out[node] = sum_ch agg[node][ch]*Wl[ch] + bl
    const int nl = tid >> 2, part = tid & 3;
    const int node = b * 64 + nl;
    float partial = 0.f;
#pragma unroll
    for (int j = 0; j < 16; ++j)
        partial = fmaf(__uint_as_float(agg[nl * 66 + part * 16 + j]),
                       Wl[part * 16 + j], partial);
    partial += __shfl_xor(partial, 1);
    partial += __shfl_xor(partial, 2);
    if (part == 0 && node < NN) outp[node] = partial + bl[0];
}

extern "C" void kernel_launch(void* const* d_in, const int* in_sizes, int n_in,
                              void* d_out, int out_size, void* d_ws, size_t ws_size,
                              hipStream_t stream)
{
    const float* x   = (const float*)d_in[0];
    const int*   ei  = (const int*)d_in[1];
    const float* W1a = (const float*)d_in[2];
    const float* b1a = (const float*)d_in[3];
    const float* W1b = (const float*)d_in[4];
    const float* b1b = (const float*)d_in[5];
    const float* W2a = (const float*)d_in[6];
    const float* b2a = (const float*)d_in[7];
    const float* W2b = (const float*)d_in[8];
    const float* b2b = (const float*)d_in[9];
    const float* Wl  = (const float*)d_in[10];
    const float* bl  = (const float*)d_in[11];

    const int* src = ei;
    const int* dst = ei + NE;

    float* ws = (float*)d_ws;
    unsigned* A16 = (unsigned*)(ws + A_OFF);
    unsigned* Bu  = (unsigned*)(ws + B_OFF);
    unsigned* A2  = (unsigned*)(ws + G1_OFF);
    unsigned* B2  = (unsigned*)(ws + G2_OFF);
    int*      gcur = (int*)(ws + GCUR_OFF);
    unsigned* p1u  = (unsigned*)(ws + P1_OFF);

    hipMemsetAsync(gcur, 0, NB * sizeof(int), stream);

    fused_mlp1_bucket<<<FUSED_BLKS, 1024, 0, stream>>>(
        x, W1a, b1a, W1b, W2a, W2b, ws, A16, Bu, src, dst, gcur, p1u);

    edge_layer_bucket<<<NB, 256, 0, stream>>>(
        A16, Bu, p1u, gcur, (const int*)(ws + WB1F_OFF), b1b,
        (const int*)(ws + W2C_OFF), b2a, A2, B2);

    edge_layer_bucket2<<<NB, 256, 0, stream>>>(A2, B2, p1u, gcur,
                                               (const int*)(ws + WB2F_OFF), b2b,
                                               Wl, bl, (float*)d_out);
}

// Round 17
// 220.103 us; speedup vs baseline: 1.3319x; 1.3319x over previous
//
#include <hip/hip_runtime.h>
#include <hip/hip_fp16.h>

#define NN 100000
#define NE 1600000
#define N64 (NN * 64)
#define NB 1563                       // buckets = dst>>6 (ceil(100000/64))
#define CAP2 1280                     // bucket capacity (mean ~1024, +8 sigma)
#define P1STRIDE (CAP2 * 2)           // dwords per bucket slot (u32 payload + dump room)
#define MLP1_BLKS 391                 // mlp1 role: block covers 256 nodes x 4 quarters
#define BKT_BLKS 196                  // 196 * 1024 * 8 >= NE
#define FUSED_BLKS 588                // 2:1 interleave grid (one idle mlp1 slot)
#define MAXT 148                      // max tiles/bucket: 64 + (1280-64)/16 = 140, +pad

typedef __attribute__((ext_vector_type(8))) _Float16 f16x8;
typedef __attribute__((ext_vector_type(4))) float fx4;

// ---- workspace layout (dword offsets) ----
#define W1D_OFF 0
#define W1S_OFF 448
#define WB1F_OFF 9216                 // f16 Wb frags layer1: 2048 dwords
#define WB2F_OFF 11264                // layer2: 2048 dwords
#define W2C_OFF 13312                 // combined f16 W2a frags (Wd||Ws): 4096 dwords
#define GCUR_OFF 17408                // bucket cursors [NB]
#define A_OFF   32768                 // packed f16: 32 dwords/node (layer-1 A)
#define B_OFF   (A_OFF + N64 / 2)     // layer-1 B
#define G1_OFF  (B_OFF + N64 / 2)     // layer-2 A features (written by edge1 epilogue)
#define G2_OFF  (G1_OFF + N64 / 2)    // layer-2 B features
#define P1_OFF  (G2_OFF + N64 / 2)    // u32[NB*P1STRIDE] bucket staging
// p1 slot (P1STRIDE dwords per bucket):
//   scatter phase: [0..size)  u32 payload = src | dloc<<17  (src<2^17, dloc 6b)
//   after layer-1 sort dump:  [0..CAP2) sorted src ids; [CAP2] = T;
//                             [CAP2+1..CAP2+1+MAXT) tile descriptors
// Determinism note (R38 audit): the only run-to-run variation is scatter
// ORDER within bucket/node segments; tile counts are order-invariant, each
// edge's message is row-independent in the MFMA, and the atomicMax
// aggregation is associative/commutative -> output is bit-deterministic.

union FragH { unsigned u[4]; f16x8 f; };

static __device__ __forceinline__ unsigned pack_h2(float f0, float f1) {
    __half h0 = __float2half_rn(f0), h1 = __float2half_rn(f1);
    unsigned short u0 = *(unsigned short*)&h0, u1 = *(unsigned short*)&h1;
    return (unsigned)u0 | ((unsigned)u1 << 16);
}

// Prep: zero bucket cursors, precombine W1a, build f16 Wb frags + combined
// layer-2 node-MLP weight frags (Wd = top-bottom || Ws = bottom).
__global__ __launch_bounds__(256) void prep_all(
    const float* __restrict__ W1a, const float* __restrict__ W1b,
    const float* __restrict__ W2a, const float* __restrict__ W2b,
    float* __restrict__ ws, int* __restrict__ gcur)
{
    int t = blockIdx.x * 256 + threadIdx.x;
    if (t < NB) gcur[t] = 0;
    if (t < 448) {
        float top = W1a[t], bot = W1a[448 + t];
        ws[W1D_OFF + t] = top - bot;
        ws[W1S_OFF + t] = bot;
    }
    if (t < 1024) {
        int layer = t >> 9;
        int r = t & 511;
        int ks = (r >> 8) & 1, nt = (r >> 6) & 3, lane = r & 63;
        const float* Wb = layer ? W2b : W1b;
        int* out = (int*)(ws + (layer ? WB2F_OFF : WB1F_OFF));
        int quad = lane >> 4, c = lane & 15, n = nt * 16 + c;
        unsigned dw[4];
#pragma unroll
        for (int d = 0; d < 4; ++d) {
            int k0 = quad * 8 + d * 2 + 32 * ks;
            dw[d] = pack_h2(Wb[k0 * 64 + n], Wb[(k0 + 1) * 64 + n]);
        }
        ((int4*)out)[r] = make_int4((int)dw[0], (int)dw[1], (int)dw[2], (int)dw[3]);
    }
    if (t >= 1024 && t < 2048) {
        int r = t - 1024;                       // ks*512 + nt*64 + lane
        int ks = (r >> 9) & 1, nt8 = (r >> 6) & 7, lane = r & 63;
        int quad = lane >> 4, c = lane & 15;
        int ncol = nt8 * 16 + c;                // 0..127
        int* out = (int*)(ws + W2C_OFF);
        unsigned dw[4];
#pragma unroll
        for (int d = 0; d < 4; ++d) {
            unsigned v[2];
#pragma unroll
            for (int e = 0; e < 2; ++e) {
                int k = quad * 8 + d * 2 + e + 32 * ks;
                float w = (ncol < 64)
                    ? (W2a[k * 64 + ncol] - W2a[(64 + k) * 64 + ncol])
                    : W2a[(64 + k) * 64 + (ncol - 64)];
                __half h = __float2half_rn(w);
                v[e] = *(unsigned short*)&h;
            }
            dw[d] = (v[1] << 16) | v[0];
        }
        ((int4*)out)[r] = make_int4((int)dw[0], (int)dw[1], (int)dw[2], (int)dw[3]);
    }
}

// Fused mlp1 + bucket multisplit (R35-exact, measured best 222.16us).
// 2:1 interleave by blockIdx: r=idx%3, r==2 -> bucket g=idx/3 (196 blocks);
// else mlp1 id=2g+r (0..391, one guarded idle). The fused kernel is
// HBM-bound on the p1 random scatter (4B writes dirty 64B lines); mlp1-role
// compute tweaks are invisible behind it (R30 lesson).
__global__ __launch_bounds__(1024) void fused_mlp1_bucket(
    const float* __restrict__ x, const float* __restrict__ Wd,
    const float* __restrict__ Ws, const float* __restrict__ ba,
    unsigned* __restrict__ A16, unsigned* __restrict__ Bu,
    const int* __restrict__ src, const int* __restrict__ dst,
    int* __restrict__ gcur, unsigned* __restrict__ p1u)
{
    __shared__ int cnt[NB];
    __shared__ int cur[NB];
    const int t = threadIdx.x;
    const int g = blockIdx.x / 3, r = blockIdx.x % 3;

    if (r != 2) {
        const int mid = 2 * g + r;               // mlp1 role
        if (mid >= MLP1_BLKS) return;
        const int q = t >> 8;
        const int i = mid * 256 + (t & 255);
        if (i >= NN) return;
        float xv[7];
#pragma unroll
        for (int k = 0; k < 7; ++k) xv[k] = x[i * 7 + k];
        uint4* pa = (uint4*)(A16 + (size_t)i * 32 + q * 8);
        uint4* pb = (uint4*)(Bu + (size_t)i * 32 + q * 8);
        float acc[16];
#pragma unroll
        for (int c = 0; c < 16; ++c) acc[c] = ba[q * 16 + c];
#pragma unroll
        for (int k = 0; k < 7; ++k)
#pragma unroll
            for (int c = 0; c < 16; ++c)
                acc[c] = fmaf(xv[k], Wd[k * 64 + q * 16 + c], acc[c]);
        pa[0] = make_uint4(pack_h2(acc[0], acc[1]),  pack_h2(acc[2], acc[3]),
                           pack_h2(acc[4], acc[5]),  pack_h2(acc[6], acc[7]));
        pa[1] = make_uint4(pack_h2(acc[8], acc[9]),  pack_h2(acc[10], acc[11]),
                           pack_h2(acc[12], acc[13]), pack_h2(acc[14], acc[15]));
#pragma unroll
        for (int c = 0; c < 16; ++c) acc[c] = 0.0f;
#pragma unroll
        for (int k = 0; k < 7; ++k)
#pragma unroll
            for (int c = 0; c < 16; ++c)
                acc[c] = fmaf(xv[k], Ws[k * 64 + q * 16 + c], acc[c]);
        pb[0] = make_uint4(pack_h2(acc[0], acc[1]),  pack_h2(acc[2], acc[3]),
                           pack_h2(acc[4], acc[5]),  pack_h2(acc[6], acc[7]));
        pb[1] = make_uint4(pack_h2(acc[8], acc[9]),  pack_h2(acc[10], acc[11]),
                           pack_h2(acc[12], acc[13]), pack_h2(acc[14], acc[15]));
        return;
    }

    // ---- bucket role (bb = g) ----
    const int e0 = (g * 1024 + t) * 8;
    const bool ok = (e0 < NE);                   // NE % 8 == 0
    for (int i = t; i < NB; i += 1024) cnt[i] = 0;
    int ss[8], dd[8], bk[8];
    if (ok) {
        int4 d0 = ((const int4*)(dst + e0))[0];
        int4 d1 = ((const int4*)(dst + e0))[1];
        int4 s0 = ((const int4*)(src + e0))[0];
        int4 s1 = ((const int4*)(src + e0))[1];
        dd[0]=d0.x; dd[1]=d0.y; dd[2]=d0.z; dd[3]=d0.w;
        dd[4]=d1.x; dd[5]=d1.y; dd[6]=d1.z; dd[7]=d1.w;
        ss[0]=s0.x; ss[1]=s0.y; ss[2]=s0.z; ss[3]=s0.w;
        ss[4]=s1.x; ss[5]=s1.y; ss[6]=s1.z; ss[7]=s1.w;
    }
    __syncthreads();
    if (ok) {
#pragma unroll
        for (int j = 0; j < 8; ++j) { bk[j] = dd[j] >> 6; atomicAdd(&cnt[bk[j]], 1); }
    }
    __syncthreads();
    for (int i = t; i < NB; i += 1024)
        cur[i] = atomicAdd(&gcur[i], cnt[i]);    // reserve block ranges
    __syncthreads();
    if (ok) {
#pragma unroll
        for (int j = 0; j < 8; ++j) {
            int pos = atomicAdd(&cur[bk[j]], 1);
            p1u[(size_t)bk[j] * P1STRIDE + pos] =
                (unsigned)ss[j] | ((unsigned)(dd[j] & 63) << 17);
        }
    }
}

// ---- shared phase-4 tile loop (R29-exact: 2 tiles/wave-iter, register wf).
// Pipelining attempts (R20, R34) both measured neutral; occupancy >4 blocks
// spills (R23/R24/R32). This is the measured-best structure.
#define EDGE_PHASE4                                                           \
    const int nb64 = b * 64;                                                  \
    for (int t0 = wv * 2; t0 < T; t0 += 8) {                                  \
        const int2 tp = ((const int2*)tiles)[t0 >> 1];                        \
        const int n0 = tp.x & 63, ba0 = (tp.x >> 6) & 2047, c0 = tp.x >> 17;  \
        const int n1 = tp.y & 63, ba1 = (tp.y >> 6) & 2047, c1 = tp.y >> 17;  \
        const int s0 = ssrc[ba0 + min(c15, c0 - 1)];                          \
        const int s1 = ssrc[ba1 + min(c15, c1 - 1)];                          \
        const unsigned* pa0 = A16 + (size_t)(nb64 + n0) * 32 + quad * 4;      \
        const unsigned* pa1 = A16 + (size_t)(nb64 + n1) * 32 + quad * 4;      \
        const unsigned* pb0 = Bu + (size_t)s0 * 32 + quad * 4;                \
        const unsigned* pb1 = Bu + (size_t)s1 * 32 + quad * 4;                \
        uint4 ga[2][2], gb[2][2];                                             \
        _Pragma("unroll")                                                     \
        for (int ks = 0; ks < 2; ++ks) {                                      \
            ga[0][ks] = ((const uint4*)(pa0 + ks * 16))[0];                   \
            gb[0][ks] = ((const uint4*)(pb0 + ks * 16))[0];                   \
            ga[1][ks] = ((const uint4*)(pa1 + ks * 16))[0];                   \
            gb[1][ks] = ((const uint4*)(pb1 + ks * 16))[0];                   \
        }                                                                     \
        FragH tf[2][2];                                                       \
        _Pragma("unroll")                                                     \
        for (int mt = 0; mt < 2; ++mt)                                        \
            _Pragma("unroll")                                                 \
            for (int ks = 0; ks < 2; ++ks) {                                  \
                FragH ua, ub;                                                 \
                ua.u[0] = ga[mt][ks].x; ua.u[1] = ga[mt][ks].y;               \
                ua.u[2] = ga[mt][ks].z; ua.u[3] = ga[mt][ks].w;               \
                ub.u[0] = gb[mt][ks].x; ub.u[1] = gb[mt][ks].y;               \
                ub.u[2] = gb[mt][ks].z; ub.u[3] = gb[mt][ks].w;               \
                f16x8 s = ua.f + ub.f;                                        \
                tf[mt][ks].f = __builtin_elementwise_max(                     \
                    s, (f16x8)(_Float16)0.0f);                                \
            }                                                                 \
        fx4 acc[2][4];                                                        \
        _Pragma("unroll")                                                     \
        for (int mt = 0; mt < 2; ++mt)                                        \
            _Pragma("unroll")                                                 \
            for (int nt = 0; nt < 4; ++nt)                                    \
                acc[mt][nt] = (fx4){0.f, 0.f, 0.f, 0.f};                      \
        _Pragma("unroll")                                                     \
        for (int ks = 0; ks < 2; ++ks)                                        \
            _Pragma("unroll")                                                 \
            for (int mt = 0; mt < 2; ++mt)                                    \
                _Pragma("unroll")                                             \
                for (int nt = 0; nt < 4; ++nt)                                \
                    acc[mt][nt] = __builtin_amdgcn_mfma_f32_16x16x32_f16(     \
                        tf[mt][ks].f, wf[ks][nt].f, acc[mt][nt], 0, 0, 0);    \
        const bool qb0 = (quad & 1) != 0, qb1 = (quad & 2) != 0;              \
        _Pragma("unroll")                                                     \
        for (int mt = 0; mt < 2; ++mt) {                                      \
            float rr[4];                                                      \
            _Pragma("unroll")                                                 \
            for (int nt = 0; nt < 4; ++nt)                                    \
                rr[nt] = fmaxf(fmaxf(acc[mt][nt][0], acc[mt][nt][1]),         \
                               fmaxf(acc[mt][nt][2], acc[mt][nt][3]));        \
            float u;                                                          \
            u = __shfl_xor(qb0 ? rr[0] : rr[1], 16);                          \
            if (qb0) rr[0] = u; else rr[1] = u;                               \
            u = __shfl_xor(qb0 ? rr[2] : rr[3], 16);                          \
            if (qb0) rr[2] = u; else rr[3] = u;                               \
            u = __shfl_xor(qb1 ? rr[0] : rr[2], 32);                          \
            if (qb1) rr[0] = u; else rr[2] = u;                               \
            u = __shfl_xor(qb1 ? rr[1] : rr[3], 32);                          \
            if (qb1) rr[1] = u; else rr[3] = u;                               \
            const float v = fmaxf(fmaxf(rr[0], rr[1]), fmaxf(rr[2], rr[3]));  \
            const float h = fmaxf(v + bcol, 0.f);                             \
            const int n = mt ? n1 : n0;                                       \
            atomicMax(&agg[n * 66 + lane], __float_as_uint(h));               \
        }                                                                     \
    }

// Edge layer 1 (sort + save + fused node-MLP2): node-major tiles after
// in-LDS counting sort; sorted ssrc/tiles dumped to the p1 slot for layer 2.
// Epilogue pushes the relu'd 64x64 agg tile through the [64->128] node-MLP2
// GEMM -> A2/B2 (must NOT touch A16/Bu: other blocks still gather them).
// LAUNCH BOUNDS LAW (R18/R22/R23/R24/R32): arch-VGPR cap ~= 512/(2N):
//   bound 4 -> 64 (FITS); bound 5 -> 48 (SPILLS even with wf in LDS, R32);
//   bound 6/7 -> 40/36 (heavy spill). THIS BODY STAYS AT BOUND 4.
__global__ __launch_bounds__(256, 4) void edge_layer_bucket(
    const unsigned* __restrict__ A16, const unsigned* __restrict__ Bu,
    unsigned* __restrict__ p1u, const int* __restrict__ gcnt,
    const int* __restrict__ wbf, const float* __restrict__ bb,
    const int* __restrict__ wcf, const float* __restrict__ ba2,
    unsigned* __restrict__ A2, unsigned* __restrict__ B2)
{
    __shared__ unsigned agg[64 * 66];            // 16,896 B
    __shared__ int cnt[64];
    __shared__ int cur[64];
    __shared__ int ssrc[CAP2];                   // 5,120 B
    __shared__ __align__(8) int tiles[MAXT];
    __shared__ int tcnt_s;

    const int tid = threadIdx.x;
    const int wv = tid >> 6, lane = tid & 63;
    const int quad = lane >> 4, c15 = lane & 15;
    const int b = blockIdx.x;
    const int size = min(gcnt[b], CAP2);         // clamp: never OOB ssrc/tiles
    const unsigned* bp = p1u + (size_t)b * P1STRIDE;

    for (int i = tid; i < 64 * 66; i += 256) agg[i] = 0u;
    if (tid < 64) cnt[tid] = 0;

    FragH wf[2][4];                              // persistent weight frags
#pragma unroll
    for (int ks = 0; ks < 2; ++ks)
#pragma unroll
        for (int nt = 0; nt < 4; ++nt) {
            int4 v = ((const int4*)wbf)[(ks * 4 + nt) * 64 + lane];
            wf[ks][nt].u[0] = (unsigned)v.x; wf[ks][nt].u[1] = (unsigned)v.y;
            wf[ks][nt].u[2] = (unsigned)v.z; wf[ks][nt].u[3] = (unsigned)v.w;
        }
    const float bcol = bb[lane];                 // channel == lane
    __syncthreads();

    // ---- phase 1: histogram (payload = src | dloc<<17) ----
    for (int i = tid; i < size; i += 256)
        atomicAdd(&cnt[bp[i] >> 17], 1);
    __syncthreads();

    // ---- phase 2: scan + tile list (wave 0 only) ----
    if (tid < 64) {
        const int c = cnt[tid];
        int x = c;
#pragma unroll
        for (int d = 1; d < 64; d <<= 1) {
            int y = __shfl_up(x, d, 64);
            if (lane >= d) x += y;
        }
        const int rs = x - c;                    // exclusive prefix (row start)
        cur[tid] = rs;
        const int ntl = (c + 15) >> 4;
        int tx = ntl;
#pragma unroll
        for (int d = 1; d < 64; d <<= 1) {
            int y = __shfl_up(tx, d, 64);
            if (lane >= d) tx += y;
        }
        const int tb = tx - ntl;
        for (int k = 0; k < ntl; ++k)            // node | base<<6 | cnt<<17
            tiles[tb + k] = tid | ((rs + 16 * k) << 6) | (min(16, c - 16 * k) << 17);
        if (tid == 63) tcnt_s = tx;
    }
    __syncthreads();
    const int T = tcnt_s;
    if (tid == 0 && T > 0) tiles[T] = tiles[T - 1];   // pad for int2 pair read

    // ---- phase 3: scatter src ids node-major ----
    __syncthreads();
    for (int i = tid; i < size; i += 256) {
        const unsigned w = bp[i];
        int p = atomicAdd(&cur[w >> 17], 1);
        ssrc[p] = (int)(w & 0x1FFFF);
    }
    __syncthreads();

    // ---- dump sorted order into this bucket's (now dead) p1 slot.
    // All bp reads completed before the barrier above; slot is block-private.
    {
        unsigned* dump = p1u + (size_t)b * P1STRIDE;
        for (int i = tid; i < size; i += 256) dump[i] = (unsigned)ssrc[i];
        if (tid == 0) dump[CAP2] = (unsigned)T;
        if (tid < MAXT) dump[CAP2 + 1 + tid] = (unsigned)tiles[tid];
    }

    EDGE_PHASE4
    __syncthreads();

    // ---- fused node-MLP2 epilogue: X = relu'd agg [64x64] -> A2/B2 [->128].
    // A-frag layout per node_mlp2's proven pattern: row = c15 (within this
    // wave's 16-node M-tile), k = ks*32 + quad*8 + (0..7).
    {
        const int arow = wv * 16 + c15;
        FragH xa[2];
#pragma unroll
        for (int ks = 0; ks < 2; ++ks) {
            const unsigned* ag = &agg[arow * 66 + ks * 32 + quad * 8];
#pragma unroll
            for (int d = 0; d < 4; ++d)
                xa[ks].u[d] = pack_h2(__uint_as_float(ag[2 * d]),
                                      __uint_as_float(ag[2 * d + 1]));
        }
        __half* Ah = (__half*)A2;
        __half* Bh = (__half*)B2;
#pragma unroll
        for (int nt = 0; nt < 8; ++nt) {
            FragH w0, w1;
            int4 v0 = ((const int4*)wcf)[nt * 64 + lane];
            int4 v1 = ((const int4*)wcf)[(8 + nt) * 64 + lane];
            w0.u[0] = (unsigned)v0.x; w0.u[1] = (unsigned)v0.y;
            w0.u[2] = (unsigned)v0.z; w0.u[3] = (unsigned)v0.w;
            w1.u[0] = (unsigned)v1.x; w1.u[1] = (unsigned)v1.y;
            w1.u[2] = (unsigned)v1.z; w1.u[3] = (unsigned)v1.w;
            fx4 acc2 = (fx4){0.f, 0.f, 0.f, 0.f};
            acc2 = __builtin_amdgcn_mfma_f32_16x16x32_f16(xa[0].f, w0.f, acc2, 0, 0, 0);
            acc2 = __builtin_amdgcn_mfma_f32_16x16x32_f16(xa[1].f, w1.f, acc2, 0, 0, 0);
            const float bbv = (nt < 4) ? ba2[nt * 16 + c15] : 0.f;
            __half* outh = (nt < 4) ? Ah : Bh;
            const int ch = (nt & 3) * 16 + c15;
#pragma unroll
            for (int r = 0; r < 4; ++r) {
                const int node = b * 64 + wv * 16 + quad * 4 + r;
                if (node < NN)
                    outh[(size_t)node * 64 + ch] = __float2half_rn(acc2[r] + bbv);
            }
        }
    }
}

// Edge layer 2 (load pre-sorted) + fused final linear: skips phases 1-3 via
// the p1 dump; writeout computes out[node] = h2 . Wl + bl directly from the
// relu'd agg rows in LDS (4 threads/node, 16-ch partials, 2x shfl_xor).
__global__ __launch_bounds__(256, 4) void edge_layer_bucket2(
    const unsigned* __restrict__ A16, const unsigned* __restrict__ Bu,
    const unsigned* __restrict__ p1s, const int* __restrict__ gcnt,
    const int* __restrict__ wbf, const float* __restrict__ bb,
    const float* __restrict__ Wl, const float* __restrict__ bl,
    float* __restrict__ outp)
{
    __shared__ unsigned agg[64 * 66];            // 16,896 B
    __shared__ int ssrc[CAP2];                   // 5,120 B
    __shared__ __align__(8) int tiles[MAXT];
    __shared__ int tcnt_s;

    const int tid = threadIdx.x;
    const int wv = tid >> 6, lane = tid & 63;
    const int quad = lane >> 4, c15 = lane & 15;
    const int b = blockIdx.x;
    const int size = min(gcnt[b], CAP2);
    const unsigned* slot = p1s + (size_t)b * P1STRIDE;

    for (int i = tid; i < 64 * 66; i += 256) agg[i] = 0u;
    if (tid == 0) tcnt_s = (int)slot[CAP2];
    if (tid < MAXT) tiles[tid] = (int)slot[CAP2 + 1 + tid];
    for (int i = tid; i < size; i += 256) ssrc[i] = (int)slot[i];

    FragH wf[2][4];
#pragma unroll
    for (int ks = 0; ks < 2; ++ks)
#pragma unroll
        for (int nt = 0; nt < 4; ++nt) {
            int4 v = ((const int4*)wbf)[(ks * 4 + nt) * 64 + lane];
            wf[ks][nt].u[0] = (unsigned)v.x; wf[ks][nt].u[1] = (unsigned)v.y;
            wf[ks][nt].u[2] = (unsigned)v.z; wf[ks][nt].u[3] = (unsigned)v.w;
        }
    const float bcol = bb[lane];
    __syncthreads();
    const int T = tcnt_s;

    EDGE_PHASE4
    __syncthreads();

    // fused final linear: out[node] = sum_ch agg[node][ch]*Wl[ch] + bl
    const int nl = tid >> 2, part = tid & 3;
    const int node = b * 64 + nl;
    float partial = 0.f;
#pragma unroll
    for (int j = 0; j < 16; ++j)
        partial = fmaf(__uint_as_float(agg[nl * 66 + part * 16 + j]),
                       Wl[part * 16 + j], partial);
    partial += __shfl_xor(partial, 1);
    partial += __shfl_xor(partial, 2);
    if (part == 0 && node < NN) outp[node] = partial + bl[0];
}

extern "C" void kernel_launch(void* const* d_in, const int* in_sizes, int n_in,
                              void* d_out, int out_size, void* d_ws, size_t ws_size,
                              hipStream_t stream)
{
    const float* x   = (const float*)d_in[0];
    const int*   ei  = (const int*)d_in[1];
    const float* W1a = (const float*)d_in[2];
    const float* b1a = (const float*)d_in[3];
    const float* W1b = (const float*)d_in[4];
    const float* b1b = (const float*)d_in[5];
    const float* W2a = (const float*)d_in[6];
    const float* b2a = (const float*)d_in[7];
    const float* W2b = (const float*)d_in[8];
    const float* b2b = (const float*)d_in[9];
    const float* Wl  = (const float*)d_in[10];
    const float* bl  = (const float*)d_in[11];

    const int* src = ei;
    const int* dst = ei + NE;

    float* ws = (float*)d_ws;
    unsigned* A16 = (unsigned*)(ws + A_OFF);
    unsigned* Bu  = (unsigned*)(ws + B_OFF);
    unsigned* A2  = (unsigned*)(ws + G1_OFF);
    unsigned* B2  = (unsigned*)(ws + G2_OFF);
    int*      gcur = (int*)(ws + GCUR_OFF);
    unsigned* p1u  = (unsigned*)(ws + P1_OFF);

    prep_all<<<16, 256, 0, stream>>>(W1a, W1b, W2a, W2b, ws, gcur);

    fused_mlp1_bucket<<<FUSED_BLKS, 1024, 0, stream>>>(
        x, ws + W1D_OFF, ws + W1S_OFF, b1a, A16, Bu, src, dst, gcur, p1u);

    edge_layer_bucket<<<NB, 256, 0, stream>>>(
        A16, Bu, p1u, gcur, (const int*)(ws + WB1F_OFF), b1b,
        (const int*)(ws + W2C_OFF), b2a, A2, B2);

    edge_layer_bucket2<<<NB, 256, 0, stream>>>(A2, B2, p1u, gcur,
                                               (const int*)(ws + WB2F_OFF), b2b,
                                               Wl, bl, (float*)d_out);
}